// Round 7
// baseline (929.757 us; speedup 1.0000x reference)
//
#include <hip/hip_runtime.h>
#include <hip/hip_bf16.h>
#include <cstdint>

// ---------------------------------------------------------------------------
// GCN 3-layer forward, bf16 feature pipeline + MFMA GEMM.
// R7: REVERT slab gather (FETCH 830MB, line-granularity thrash: 32B access
//     fetches 64B line -> 6.4MB/XCD footprint > 4MB L2). Back to row-parallel
//     gather (256B rows, 4 lines fully used, 190MB fetch @ R4) with uint2
//     lanes + 2 groups/wave + unroll2. Keep R6 wins: fused fp32 mean-pool in
//     last gather, GEMM0 reads fp32 x. Fused k_init (detect+zero), k_wpack3.
// ---------------------------------------------------------------------------

typedef unsigned short u16;
typedef unsigned int u32;
typedef __attribute__((ext_vector_type(8))) short short8v;
typedef __attribute__((ext_vector_type(4))) float f32x4;

#define NBMAX 256
#define BKSH  9
#define SCH   2048

__device__ inline u16 f2bf(float f) {
  u32 u = __float_as_uint(f);
  u += 0x7fff + ((u >> 16) & 1);  // RNE
  return (u16)(u >> 16);
}
__device__ inline float bflo(u32 u) { return __uint_as_float(u << 16); }
__device__ inline float bfhi(u32 u) { return __uint_as_float(u & 0xffff0000u); }

// --- init: block 0 detects edge dtype, block 1 zeros counters ---------------
__global__ void k_init(const int* __restrict__ ei, int* __restrict__ mode,
                       int* __restrict__ bucketCnt, float* __restrict__ pooled,
                       int e, int nb) {
  if (blockIdx.x == 0) {
    __shared__ int any;
    if (threadIdx.x == 0) any = 0;
    __syncthreads();
    int lim = min(e, 2048);
    int local = 0;
    for (int i = threadIdx.x; i < lim; i += blockDim.x)
      local |= (ei[2 * i + 1] != 0);
    if (local) atomicOr(&any, 1);
    __syncthreads();
    if (threadIdx.x == 0) mode[0] = (any == 0) ? 1 : 0;
  } else {
    int i = threadIdx.x;
    if (i < nb) bucketCnt[i] = 0;
    if (i < 128) pooled[i] = 0.0f;
  }
}

// --- CSR build: 2-level radix by destination --------------------------------
__global__ __launch_bounds__(256) void b_count(const int* __restrict__ ei,
                                               const int* __restrict__ mode,
                                               int* __restrict__ bucketCnt,
                                               int e, int nb) {
  __shared__ int lh[NBMAX];
  int t = threadIdx.x;
  lh[t] = 0;
  __syncthreads();
  int m = mode[0];
  int stride = gridDim.x * 256;
  for (int i = blockIdx.x * 256 + t; i < e; i += stride) {
    long long di = (long long)e + i;
    int d = m ? ei[2 * di] : ei[di];
    atomicAdd(&lh[d >> BKSH], 1);
  }
  __syncthreads();
  if (t < nb && lh[t]) atomicAdd(&bucketCnt[t], lh[t]);
}

__global__ __launch_bounds__(256) void b_bscan(const int* __restrict__ bucketCnt,
                                               int* __restrict__ bucketOff,
                                               int* __restrict__ bucketCur,
                                               int nb, int e) {
  __shared__ int sh[NBMAX];
  int t = threadIdx.x;
  int c = (t < nb) ? bucketCnt[t] : 0;
  sh[t] = c;
  __syncthreads();
  for (int d = 1; d < NBMAX; d <<= 1) {
    int v = (t >= d) ? sh[t - d] : 0;
    __syncthreads();
    sh[t] += v;
    __syncthreads();
  }
  int ex = sh[t] - c;
  if (t < nb) { bucketOff[t] = ex; bucketCur[t] = ex; }
  if (t == 0) bucketOff[nb] = e;
}

__global__ __launch_bounds__(256) void b_scatter(const int* __restrict__ ei,
                                                 const int* __restrict__ mode,
                                                 int* __restrict__ bucketCur,
                                                 int* __restrict__ pairBuf,
                                                 int e, int nb) {
  __shared__ int cnt[NBMAX];
  __shared__ int pre[NBMAX];
  __shared__ int base[NBMAX];
  __shared__ int stage[2 * SCH];
  const int t = threadIdx.x;
  const int chunk0 = blockIdx.x * SCH;
  const int nloc = min(SCH, e - chunk0);
  const int m = mode[0];

  cnt[t] = 0;
  __syncthreads();

  int myS[SCH / 256], myD[SCH / 256], myB[SCH / 256], mySlot[SCH / 256];
#pragma unroll
  for (int j = 0; j < SCH / 256; ++j) {
    int li = j * 256 + t;
    myB[j] = -1;
    if (li < nloc) {
      int i = chunk0 + li;
      long long di = (long long)e + i;
      int s = m ? ei[2 * (long long)i] : ei[i];
      int d = m ? ei[2 * di] : ei[di];
      int b = d >> BKSH;
      myS[j] = s; myD[j] = d; myB[j] = b;
      mySlot[j] = atomicAdd(&cnt[b], 1);
    }
  }
  __syncthreads();

  int c0 = cnt[t];
  pre[t] = c0;
  __syncthreads();
  for (int d = 1; d < NBMAX; d <<= 1) {
    int v = (t >= d) ? pre[t - d] : 0;
    __syncthreads();
    pre[t] += v;
    __syncthreads();
  }
  int myPre = pre[t] - c0;
  if (t < nb && c0 > 0) base[t] = atomicAdd(&bucketCur[t], c0);
  __syncthreads();
  cnt[t] = myPre;
  __syncthreads();

#pragma unroll
  for (int j = 0; j < SCH / 256; ++j) {
    if (myB[j] >= 0) {
      int si = cnt[myB[j]] + mySlot[j];
      stage[2 * si] = myS[j];
      stage[2 * si + 1] = myD[j];
    }
  }
  __syncthreads();

  int wave = t >> 6, lane = t & 63;
  for (int b = wave; b < nb; b += 4) {
    int cb = pre[b] - cnt[b];
    if (cb <= 0) continue;
    int lo = cnt[b];
    size_t gb = (size_t)base[b];
    for (int j = lane; j < 2 * cb; j += 64)
      pairBuf[2 * gb + j] = stage[2 * lo + j];
  }
}

__global__ __launch_bounds__(512) void b_fine(const int* __restrict__ pairBuf,
                                              const int* __restrict__ bucketOff,
                                              int* __restrict__ offs,
                                              float* __restrict__ dis,
                                              int* __restrict__ csr,
                                              int n, int e) {
  const int b = blockIdx.x;
  const int d0 = b << BKSH;
  const int lo = bucketOff[b], hi = bucketOff[b + 1];
  __shared__ int arr[1 << BKSH];
  __shared__ int cur[1 << BKSH];
  const int t = threadIdx.x;
  arr[t] = 0; cur[t] = 0;
  __syncthreads();
  for (int i = lo + t; i < hi; i += 512) {
    int d = pairBuf[2 * (size_t)i + 1];
    atomicAdd(&arr[d - d0], 1);
  }
  __syncthreads();
  int c0 = arr[t];
  __syncthreads();
  for (int dd = 1; dd < 512; dd <<= 1) {
    int v = (t >= dd) ? arr[t - dd] : 0;
    __syncthreads();
    arr[t] += v;
    __syncthreads();
  }
  int epre = arr[t] - c0;
  int gd = d0 + t;
  if (gd < n) {
    offs[gd] = lo + epre;
    dis[gd] = rsqrtf((float)c0 + 1.0f);
  }
  __syncthreads();
  arr[t] = epre;
  __syncthreads();
  for (int i = lo + t; i < hi; i += 512) {
    int s = pairBuf[2 * (size_t)i];
    int d = pairBuf[2 * (size_t)i + 1];
    int ld = d - d0;
    int p = lo + arr[ld] + atomicAdd(&cur[ld], 1);
    csr[p] = s;
  }
  if (b == 0 && t == 0) offs[n] = e;
}

// --- pack all 3 weights fp32 -> MFMA B-fragments bf16 (grid 24) -------------
__global__ __launch_bounds__(256) void k_wpack3(const float* __restrict__ W0,
                                                const float* __restrict__ W1,
                                                const float* __restrict__ W2,
                                                u16* __restrict__ wp) {
  int f = blockIdx.x * 256 + threadIdx.x;
  int wsel = f >> 11;
  int li = f & 2047;
  const float* W = (wsel == 0) ? W0 : (wsel == 1) ? W1 : W2;
  u16* dst = wp + (size_t)wsel * 2048 * 8;
  int ct = li >> 8, kc = (li >> 6) & 3, lane = li & 63;
  int g = lane >> 4, c = lane & 15;
  u32 o[4];
#pragma unroll
  for (int q = 0; q < 4; ++q) {
    int k = kc * 32 + g * 8 + q * 2;
    u16 e0 = f2bf(W[(size_t)k * 128 + ct * 16 + c]);
    u16 e1 = f2bf(W[(size_t)(k + 1) * 128 + ct * 16 + c]);
    o[q] = (u32)e0 | ((u32)e1 << 16);
  }
  uint4 v; v.x = o[0]; v.y = o[1]; v.z = o[2]; v.w = o[3];
  *reinterpret_cast<uint4*>(dst + (size_t)li * 8) = v;
}

// --- GEMM: tmp[r,:] = bf16( dis[r] * (h[r,:] @ W) ) via MFMA ----------------
template <bool FP32IN>
__global__ __launch_bounds__(256) void k_gemm_mfma(const void* __restrict__ hin,
                                                   const u16* __restrict__ wp,
                                                   const float* __restrict__ dis,
                                                   u16* __restrict__ tmpb, int n) {
  __shared__ float eps[64 * 132];
  const int tid = threadIdx.x;
  const int w = tid >> 6, l = tid & 63;
  const int g = l >> 4, c16 = l & 15;
  const int rowbase = blockIdx.x * 64 + w * 16;

  const short8v zero8 = {0, 0, 0, 0, 0, 0, 0, 0};
  short8v a[4];
  int ar = rowbase + c16;
  bool aok = ar < n;
#pragma unroll
  for (int kc = 0; kc < 4; ++kc) {
    if (FP32IN) {
      const float* hrow = (const float*)hin + (size_t)ar * 128;
      short8v s = zero8;
      if (aok) {
        float4 v0 = *reinterpret_cast<const float4*>(hrow + kc * 32 + g * 8);
        float4 v1 = *reinterpret_cast<const float4*>(hrow + kc * 32 + g * 8 + 4);
        s[0] = (short)f2bf(v0.x); s[1] = (short)f2bf(v0.y);
        s[2] = (short)f2bf(v0.z); s[3] = (short)f2bf(v0.w);
        s[4] = (short)f2bf(v1.x); s[5] = (short)f2bf(v1.y);
        s[6] = (short)f2bf(v1.z); s[7] = (short)f2bf(v1.w);
      }
      a[kc] = s;
    } else {
      const u16* hrow = (const u16*)hin + (size_t)ar * 128;
      a[kc] = aok ? *reinterpret_cast<const short8v*>(hrow + kc * 32 + g * 8) : zero8;
    }
  }

  f32x4 acc[8];
#pragma unroll
  for (int ct = 0; ct < 8; ++ct) acc[ct] = f32x4{0.f, 0.f, 0.f, 0.f};

#pragma unroll
  for (int ct = 0; ct < 8; ++ct) {
#pragma unroll
    for (int kc = 0; kc < 4; ++kc) {
      short8v b = *reinterpret_cast<const short8v*>(wp + ((size_t)(ct * 4 + kc) * 64 + l) * 8);
      acc[ct] = __builtin_amdgcn_mfma_f32_16x16x32_bf16(a[kc], b, acc[ct], 0, 0, 0);
    }
  }

#pragma unroll
  for (int j = 0; j < 4; ++j) {
    int rl = w * 16 + g * 4 + j;
    int gr = blockIdx.x * 64 + rl;
    float dn = (gr < n) ? dis[gr] : 0.f;
#pragma unroll
    for (int ct = 0; ct < 8; ++ct)
      eps[rl * 132 + ct * 16 + c16] = acc[ct][j] * dn;
  }
  __syncthreads();

  int rl = tid >> 2, seg = tid & 3;
  int gr = blockIdx.x * 64 + rl;
  if (gr < n) {
    const float* src = &eps[rl * 132 + seg * 32];
#pragma unroll
    for (int q = 0; q < 4; ++q) {
      float4 v0 = *reinterpret_cast<const float4*>(src + q * 8);
      float4 v1 = *reinterpret_cast<const float4*>(src + q * 8 + 4);
      uint4 o;
      o.x = (u32)f2bf(v0.x) | ((u32)f2bf(v0.y) << 16);
      o.y = (u32)f2bf(v0.z) | ((u32)f2bf(v0.w) << 16);
      o.z = (u32)f2bf(v1.x) | ((u32)f2bf(v1.y) << 16);
      o.w = (u32)f2bf(v1.z) | ((u32)f2bf(v1.w) << 16);
      *reinterpret_cast<uint4*>(tmpb + (size_t)gr * 128 + seg * 32 + q * 8) = o;
    }
  }
}

// --- row-parallel gather -----------------------------------------------------
// one wave per node; 2 groups of 32 lanes, uint2 (8B) per lane -> each group
// reads a full 256B row (4 lines, fully used). Groups take alternating edges,
// unroll2 -> 4 row loads in flight per wave. Cross-group combine via shfl_xor.
// POOL: last layer accumulates fp32 relu outputs into mean-pool partials.
template <bool POOL>
__global__ __launch_bounds__(256) void k_gather_row(const u16* __restrict__ tmpb,
                                                    const int* __restrict__ csr,
                                                    const int* __restrict__ offs,
                                                    const float* __restrict__ dis,
                                                    const float* __restrict__ bias,
                                                    u16* __restrict__ houtb,
                                                    float* __restrict__ pooled,
                                                    int n) {
  __shared__ float pp[128];
  const int tid = threadIdx.x;
  if (POOL) {
    if (tid < 128) pp[tid] = 0.f;
    __syncthreads();
  }
  const int nd = blockIdx.x * 4 + (tid >> 6);
  const int lane = tid & 63;
  const int g = lane >> 5, l32 = lane & 31;
  const uint2* tp = reinterpret_cast<const uint2*>(tmpb);

  float a0 = 0.f, a1 = 0.f, a2 = 0.f, a3 = 0.f;
  float c0 = 0.f, c1 = 0.f, c2 = 0.f, c3 = 0.f;
  if (nd < n) {
    const int s1 = offs[nd + 1];
    int ee = offs[nd] + g;
    for (; ee + 2 < s1; ee += 4) {
      uint2 ua = tp[(size_t)csr[ee] * 32 + l32];
      uint2 ub = tp[(size_t)csr[ee + 2] * 32 + l32];
      a0 += bflo(ua.x); a1 += bfhi(ua.x); a2 += bflo(ua.y); a3 += bfhi(ua.y);
      c0 += bflo(ub.x); c1 += bfhi(ub.x); c2 += bflo(ub.y); c3 += bfhi(ub.y);
    }
    if (ee < s1) {
      uint2 ua = tp[(size_t)csr[ee] * 32 + l32];
      a0 += bflo(ua.x); a1 += bfhi(ua.x); a2 += bflo(ua.y); a3 += bfhi(ua.y);
    }
  }
  a0 += c0; a1 += c1; a2 += c2; a3 += c3;
  // combine the two 32-lane groups (all lanes participate)
  a0 += __shfl_xor(a0, 32);
  a1 += __shfl_xor(a1, 32);
  a2 += __shfl_xor(a2, 32);
  a3 += __shfl_xor(a3, 32);

  if (nd < n && g == 0) {
    uint2 us = tp[(size_t)nd * 32 + l32];  // self-loop
    float sx0 = a0 + bflo(us.x);
    float sx1 = a1 + bfhi(us.x);
    float sx2 = a2 + bflo(us.y);
    float sx3 = a3 + bfhi(us.y);
    float dn = dis[nd];
    float4 bb = reinterpret_cast<const float4*>(bias)[l32];
    float r0 = fmaf(dn, sx0, bb.x); r0 = r0 > 0.f ? r0 : 0.f;
    float r1 = fmaf(dn, sx1, bb.y); r1 = r1 > 0.f ? r1 : 0.f;
    float r2 = fmaf(dn, sx2, bb.z); r2 = r2 > 0.f ? r2 : 0.f;
    float r3 = fmaf(dn, sx3, bb.w); r3 = r3 > 0.f ? r3 : 0.f;
    if (!POOL) {
      uint2 o;
      o.x = (u32)f2bf(r0) | ((u32)f2bf(r1) << 16);
      o.y = (u32)f2bf(r2) | ((u32)f2bf(r3) << 16);
      reinterpret_cast<uint2*>(houtb)[(size_t)nd * 32 + l32] = o;
    } else {
      atomicAdd(&pp[l32 * 4 + 0], r0);
      atomicAdd(&pp[l32 * 4 + 1], r1);
      atomicAdd(&pp[l32 * 4 + 2], r2);
      atomicAdd(&pp[l32 * 4 + 3], r3);
    }
  }

  if (POOL) {
    __syncthreads();
    if (tid < 128) atomicAdd(&pooled[tid], pp[tid]);
  }
}

__global__ void k_final(const float* __restrict__ pooled, const float* __restrict__ Wfc,
                        const float* __restrict__ bfc, float* __restrict__ out,
                        float invn) {
  int j = threadIdx.x;
  if (j < 32) {
    float acc = 0.f;
    for (int k = 0; k < 128; ++k) acc = fmaf(pooled[k], Wfc[k * 32 + j], acc);
    out[j] = fmaf(acc, invn, bfc[j]);
  }
}

extern "C" void kernel_launch(void* const* d_in, const int* in_sizes, int n_in,
                              void* d_out, int out_size, void* d_ws, size_t ws_size,
                              hipStream_t stream) {
  const float* x   = (const float*)d_in[0];
  const int*   ei  = (const int*)d_in[1];
  const float* W0  = (const float*)d_in[2];
  const float* b0  = (const float*)d_in[3];
  const float* W1  = (const float*)d_in[4];
  const float* b1  = (const float*)d_in[5];
  const float* W2  = (const float*)d_in[6];
  const float* b2  = (const float*)d_in[7];
  const float* Wfc = (const float*)d_in[8];
  const float* bfc = (const float*)d_in[9];

  const int n = in_sizes[0] / 128;
  const int e = in_sizes[1] / 2;
  const int nb = (n + (1 << BKSH) - 1) >> BKSH;

  char* ws = (char*)d_ws;
  size_t off = 0;
  auto alloc = [&](size_t bytes) -> void* {
    void* p = ws + off;
    off = (off + bytes + 255) & ~(size_t)255;
    return p;
  };
  int*   mode      = (int*)alloc(sizeof(int));
  int*   bucketCnt = (int*)alloc(NBMAX * 4);
  int*   bucketOff = (int*)alloc((NBMAX + 1) * 4);
  int*   bucketCur = (int*)alloc(NBMAX * 4);
  int*   offs      = (int*)alloc((size_t)(n + 1) * 4);
  float* dis       = (float*)alloc((size_t)n * 4);
  int*   csr       = (int*)alloc((size_t)e * 4);
  float* pooled    = (float*)alloc(128 * 4);
  u16*   wp        = (u16*)alloc(3 * 2048 * 8 * 2);
  u16*   tmpb      = (u16*)alloc((size_t)n * 128 * 2);
  u16*   houtb     = (u16*)alloc((size_t)n * 128 * 2);
  int*   pairBuf   = (int*)tmpb;  // alias: pairs consumed (b_fine) before gemm0

  k_init<<<2, 256, 0, stream>>>(ei, mode, bucketCnt, pooled, e, nb);
  b_count<<<192, 256, 0, stream>>>(ei, mode, bucketCnt, e, nb);
  b_bscan<<<1, 256, 0, stream>>>(bucketCnt, bucketOff, bucketCur, nb, e);
  b_scatter<<<(e + SCH - 1) / SCH, 256, 0, stream>>>(ei, mode, bucketCur, pairBuf, e, nb);
  b_fine<<<nb, 512, 0, stream>>>(pairBuf, bucketOff, offs, dis, csr, n, e);

  k_wpack3<<<24, 256, 0, stream>>>(W0, W1, W2, wp);

  int gg = (n + 63) / 64;
  int gn = (n + 3) / 4;

  // layer 0 (reads fp32 x directly)
  k_gemm_mfma<true><<<gg, 256, 0, stream>>>(x, wp, dis, tmpb, n);
  k_gather_row<false><<<gn, 256, 0, stream>>>(tmpb, csr, offs, dis, b0, houtb, pooled, n);
  // layer 1
  k_gemm_mfma<false><<<gg, 256, 0, stream>>>(houtb, wp + 2048 * 8, dis, tmpb, n);
  k_gather_row<false><<<gn, 256, 0, stream>>>(tmpb, csr, offs, dis, b1, houtb, pooled, n);
  // layer 2 (gather fuses mean-pool, no hout write)
  k_gemm_mfma<false><<<gg, 256, 0, stream>>>(houtb, wp + 2 * 2048 * 8, dis, tmpb, n);
  k_gather_row<true><<<gn, 256, 0, stream>>>(tmpb, csr, offs, dis, b2, houtb, pooled, n);

  k_final<<<1, 32, 0, stream>>>(pooled, Wfc, bfc, (float*)d_out, 1.0f / (float)n);
}

// Round 8
// 907.838 us; speedup vs baseline: 1.0241x; 1.0241x over previous
//
#include <hip/hip_runtime.h>
#include <hip/hip_bf16.h>
#include <cstdint>

// ---------------------------------------------------------------------------
// GCN 3-layer forward, bf16 feature pipeline + MFMA GEMM.
// R8: REVERT gather to R4 structure (wave-uniform csr index -> scalar s_load
//     + 4 independent row loads; R7's half-wave split made the index a vector
//     load feeding a dependent address chain: VALUBusy 42%->5%, 8x stall).
//     Kept: fused fp32 mean-pool (POOL) in last gather, k_init, k_wpack3,
//     GEMM0 reads fp32 x directly.
// ---------------------------------------------------------------------------

typedef unsigned short u16;
typedef unsigned int u32;
typedef __attribute__((ext_vector_type(8))) short short8v;
typedef __attribute__((ext_vector_type(4))) float f32x4;

#define NBMAX 256
#define BKSH  9
#define SCH   2048

__device__ inline u16 f2bf(float f) {
  u32 u = __float_as_uint(f);
  u += 0x7fff + ((u >> 16) & 1);  // RNE
  return (u16)(u >> 16);
}
__device__ inline float bflo(u32 u) { return __uint_as_float(u << 16); }
__device__ inline float bfhi(u32 u) { return __uint_as_float(u & 0xffff0000u); }

// --- init: block 0 detects edge dtype, block 1 zeros counters ---------------
__global__ void k_init(const int* __restrict__ ei, int* __restrict__ mode,
                       int* __restrict__ bucketCnt, float* __restrict__ pooled,
                       int e, int nb) {
  if (blockIdx.x == 0) {
    __shared__ int any;
    if (threadIdx.x == 0) any = 0;
    __syncthreads();
    int lim = min(e, 2048);
    int local = 0;
    for (int i = threadIdx.x; i < lim; i += blockDim.x)
      local |= (ei[2 * i + 1] != 0);
    if (local) atomicOr(&any, 1);
    __syncthreads();
    if (threadIdx.x == 0) mode[0] = (any == 0) ? 1 : 0;
  } else {
    int i = threadIdx.x;
    if (i < nb) bucketCnt[i] = 0;
    if (i < 128) pooled[i] = 0.0f;
  }
}

// --- CSR build: 2-level radix by destination --------------------------------
__global__ __launch_bounds__(256) void b_count(const int* __restrict__ ei,
                                               const int* __restrict__ mode,
                                               int* __restrict__ bucketCnt,
                                               int e, int nb) {
  __shared__ int lh[NBMAX];
  int t = threadIdx.x;
  lh[t] = 0;
  __syncthreads();
  int m = mode[0];
  int stride = gridDim.x * 256;
  for (int i = blockIdx.x * 256 + t; i < e; i += stride) {
    long long di = (long long)e + i;
    int d = m ? ei[2 * di] : ei[di];
    atomicAdd(&lh[d >> BKSH], 1);
  }
  __syncthreads();
  if (t < nb && lh[t]) atomicAdd(&bucketCnt[t], lh[t]);
}

__global__ __launch_bounds__(256) void b_bscan(const int* __restrict__ bucketCnt,
                                               int* __restrict__ bucketOff,
                                               int* __restrict__ bucketCur,
                                               int nb, int e) {
  __shared__ int sh[NBMAX];
  int t = threadIdx.x;
  int c = (t < nb) ? bucketCnt[t] : 0;
  sh[t] = c;
  __syncthreads();
  for (int d = 1; d < NBMAX; d <<= 1) {
    int v = (t >= d) ? sh[t - d] : 0;
    __syncthreads();
    sh[t] += v;
    __syncthreads();
  }
  int ex = sh[t] - c;
  if (t < nb) { bucketOff[t] = ex; bucketCur[t] = ex; }
  if (t == 0) bucketOff[nb] = e;
}

__global__ __launch_bounds__(256) void b_scatter(const int* __restrict__ ei,
                                                 const int* __restrict__ mode,
                                                 int* __restrict__ bucketCur,
                                                 int* __restrict__ pairBuf,
                                                 int e, int nb) {
  __shared__ int cnt[NBMAX];
  __shared__ int pre[NBMAX];
  __shared__ int base[NBMAX];
  __shared__ int stage[2 * SCH];
  const int t = threadIdx.x;
  const int chunk0 = blockIdx.x * SCH;
  const int nloc = min(SCH, e - chunk0);
  const int m = mode[0];

  cnt[t] = 0;
  __syncthreads();

  int myS[SCH / 256], myD[SCH / 256], myB[SCH / 256], mySlot[SCH / 256];
#pragma unroll
  for (int j = 0; j < SCH / 256; ++j) {
    int li = j * 256 + t;
    myB[j] = -1;
    if (li < nloc) {
      int i = chunk0 + li;
      long long di = (long long)e + i;
      int s = m ? ei[2 * (long long)i] : ei[i];
      int d = m ? ei[2 * di] : ei[di];
      int b = d >> BKSH;
      myS[j] = s; myD[j] = d; myB[j] = b;
      mySlot[j] = atomicAdd(&cnt[b], 1);
    }
  }
  __syncthreads();

  int c0 = cnt[t];
  pre[t] = c0;
  __syncthreads();
  for (int d = 1; d < NBMAX; d <<= 1) {
    int v = (t >= d) ? pre[t - d] : 0;
    __syncthreads();
    pre[t] += v;
    __syncthreads();
  }
  int myPre = pre[t] - c0;
  if (t < nb && c0 > 0) base[t] = atomicAdd(&bucketCur[t], c0);
  __syncthreads();
  cnt[t] = myPre;
  __syncthreads();

#pragma unroll
  for (int j = 0; j < SCH / 256; ++j) {
    if (myB[j] >= 0) {
      int si = cnt[myB[j]] + mySlot[j];
      stage[2 * si] = myS[j];
      stage[2 * si + 1] = myD[j];
    }
  }
  __syncthreads();

  int wave = t >> 6, lane = t & 63;
  for (int b = wave; b < nb; b += 4) {
    int cb = pre[b] - cnt[b];
    if (cb <= 0) continue;
    int lo = cnt[b];
    size_t gb = (size_t)base[b];
    for (int j = lane; j < 2 * cb; j += 64)
      pairBuf[2 * gb + j] = stage[2 * lo + j];
  }
}

__global__ __launch_bounds__(512) void b_fine(const int* __restrict__ pairBuf,
                                              const int* __restrict__ bucketOff,
                                              int* __restrict__ offs,
                                              float* __restrict__ dis,
                                              int* __restrict__ csr,
                                              int n, int e) {
  const int b = blockIdx.x;
  const int d0 = b << BKSH;
  const int lo = bucketOff[b], hi = bucketOff[b + 1];
  __shared__ int arr[1 << BKSH];
  __shared__ int cur[1 << BKSH];
  const int t = threadIdx.x;
  arr[t] = 0; cur[t] = 0;
  __syncthreads();
  for (int i = lo + t; i < hi; i += 512) {
    int d = pairBuf[2 * (size_t)i + 1];
    atomicAdd(&arr[d - d0], 1);
  }
  __syncthreads();
  int c0 = arr[t];
  __syncthreads();
  for (int dd = 1; dd < 512; dd <<= 1) {
    int v = (t >= dd) ? arr[t - dd] : 0;
    __syncthreads();
    arr[t] += v;
    __syncthreads();
  }
  int epre = arr[t] - c0;
  int gd = d0 + t;
  if (gd < n) {
    offs[gd] = lo + epre;
    dis[gd] = rsqrtf((float)c0 + 1.0f);
  }
  __syncthreads();
  arr[t] = epre;
  __syncthreads();
  for (int i = lo + t; i < hi; i += 512) {
    int s = pairBuf[2 * (size_t)i];
    int d = pairBuf[2 * (size_t)i + 1];
    int ld = d - d0;
    int p = lo + arr[ld] + atomicAdd(&cur[ld], 1);
    csr[p] = s;
  }
  if (b == 0 && t == 0) offs[n] = e;
}

// --- pack all 3 weights fp32 -> MFMA B-fragments bf16 (grid 24) -------------
__global__ __launch_bounds__(256) void k_wpack3(const float* __restrict__ W0,
                                                const float* __restrict__ W1,
                                                const float* __restrict__ W2,
                                                u16* __restrict__ wp) {
  int f = blockIdx.x * 256 + threadIdx.x;
  int wsel = f >> 11;
  int li = f & 2047;
  const float* W = (wsel == 0) ? W0 : (wsel == 1) ? W1 : W2;
  u16* dst = wp + (size_t)wsel * 2048 * 8;
  int ct = li >> 8, kc = (li >> 6) & 3, lane = li & 63;
  int g = lane >> 4, c = lane & 15;
  u32 o[4];
#pragma unroll
  for (int q = 0; q < 4; ++q) {
    int k = kc * 32 + g * 8 + q * 2;
    u16 e0 = f2bf(W[(size_t)k * 128 + ct * 16 + c]);
    u16 e1 = f2bf(W[(size_t)(k + 1) * 128 + ct * 16 + c]);
    o[q] = (u32)e0 | ((u32)e1 << 16);
  }
  uint4 v; v.x = o[0]; v.y = o[1]; v.z = o[2]; v.w = o[3];
  *reinterpret_cast<uint4*>(dst + (size_t)li * 8) = v;
}

// --- GEMM: tmp[r,:] = bf16( dis[r] * (h[r,:] @ W) ) via MFMA ----------------
template <bool FP32IN>
__global__ __launch_bounds__(256) void k_gemm_mfma(const void* __restrict__ hin,
                                                   const u16* __restrict__ wp,
                                                   const float* __restrict__ dis,
                                                   u16* __restrict__ tmpb, int n) {
  __shared__ float eps[64 * 132];
  const int tid = threadIdx.x;
  const int w = tid >> 6, l = tid & 63;
  const int g = l >> 4, c16 = l & 15;
  const int rowbase = blockIdx.x * 64 + w * 16;

  const short8v zero8 = {0, 0, 0, 0, 0, 0, 0, 0};
  short8v a[4];
  int ar = rowbase + c16;
  bool aok = ar < n;
#pragma unroll
  for (int kc = 0; kc < 4; ++kc) {
    if (FP32IN) {
      const float* hrow = (const float*)hin + (size_t)ar * 128;
      short8v s = zero8;
      if (aok) {
        float4 v0 = *reinterpret_cast<const float4*>(hrow + kc * 32 + g * 8);
        float4 v1 = *reinterpret_cast<const float4*>(hrow + kc * 32 + g * 8 + 4);
        s[0] = (short)f2bf(v0.x); s[1] = (short)f2bf(v0.y);
        s[2] = (short)f2bf(v0.z); s[3] = (short)f2bf(v0.w);
        s[4] = (short)f2bf(v1.x); s[5] = (short)f2bf(v1.y);
        s[6] = (short)f2bf(v1.z); s[7] = (short)f2bf(v1.w);
      }
      a[kc] = s;
    } else {
      const u16* hrow = (const u16*)hin + (size_t)ar * 128;
      a[kc] = aok ? *reinterpret_cast<const short8v*>(hrow + kc * 32 + g * 8) : zero8;
    }
  }

  f32x4 acc[8];
#pragma unroll
  for (int ct = 0; ct < 8; ++ct) acc[ct] = f32x4{0.f, 0.f, 0.f, 0.f};

#pragma unroll
  for (int ct = 0; ct < 8; ++ct) {
#pragma unroll
    for (int kc = 0; kc < 4; ++kc) {
      short8v b = *reinterpret_cast<const short8v*>(wp + ((size_t)(ct * 4 + kc) * 64 + l) * 8);
      acc[ct] = __builtin_amdgcn_mfma_f32_16x16x32_bf16(a[kc], b, acc[ct], 0, 0, 0);
    }
  }

#pragma unroll
  for (int j = 0; j < 4; ++j) {
    int rl = w * 16 + g * 4 + j;
    int gr = blockIdx.x * 64 + rl;
    float dn = (gr < n) ? dis[gr] : 0.f;
#pragma unroll
    for (int ct = 0; ct < 8; ++ct)
      eps[rl * 132 + ct * 16 + c16] = acc[ct][j] * dn;
  }
  __syncthreads();

  int rl = tid >> 2, seg = tid & 3;
  int gr = blockIdx.x * 64 + rl;
  if (gr < n) {
    const float* src = &eps[rl * 132 + seg * 32];
#pragma unroll
    for (int q = 0; q < 4; ++q) {
      float4 v0 = *reinterpret_cast<const float4*>(src + q * 8);
      float4 v1 = *reinterpret_cast<const float4*>(src + q * 8 + 4);
      uint4 o;
      o.x = (u32)f2bf(v0.x) | ((u32)f2bf(v0.y) << 16);
      o.y = (u32)f2bf(v0.z) | ((u32)f2bf(v0.w) << 16);
      o.z = (u32)f2bf(v1.x) | ((u32)f2bf(v1.y) << 16);
      o.w = (u32)f2bf(v1.z) | ((u32)f2bf(v1.w) << 16);
      *reinterpret_cast<uint4*>(tmpb + (size_t)gr * 128 + seg * 32 + q * 8) = o;
    }
  }
}

// --- gather (R4 structure): one wave per node, u32 (2 bf16) per lane --------
// wave-uniform edge index e -> csr loads are scalar (s_load), 4 independent
// row loads in flight. POOL: last layer accumulates fp32 relu into pool.
template <bool POOL>
__global__ __launch_bounds__(256) void k_gather_bf(const u16* __restrict__ tmpb,
                                                   const int* __restrict__ csr,
                                                   const int* __restrict__ offs,
                                                   const float* __restrict__ dis,
                                                   const float* __restrict__ bias,
                                                   u16* __restrict__ houtb,
                                                   float* __restrict__ pooled,
                                                   int n) {
  __shared__ float pp[128];
  const int tid = threadIdx.x;
  if (POOL) {
    if (tid < 128) pp[tid] = 0.f;
    __syncthreads();
  }
  int node = blockIdx.x * 4 + (tid >> 6);
  int lane = tid & 63;
  const u32* tp = reinterpret_cast<const u32*>(tmpb);

  float rx = 0.f, ry = 0.f;
  if (node < n) {
    int s0 = offs[node], s1 = offs[node + 1];
    float ax = 0.f, ay = 0.f, bx = 0.f, by = 0.f;
    float cx = 0.f, cy = 0.f, dx = 0.f, dy = 0.f;
    int e = s0;
    for (; e + 3 < s1; e += 4) {
      u32 uA = tp[(size_t)csr[e] * 64 + lane];
      u32 uB = tp[(size_t)csr[e + 1] * 64 + lane];
      u32 uC = tp[(size_t)csr[e + 2] * 64 + lane];
      u32 uD = tp[(size_t)csr[e + 3] * 64 + lane];
      ax += bflo(uA); ay += bfhi(uA); bx += bflo(uB); by += bfhi(uB);
      cx += bflo(uC); cy += bfhi(uC); dx += bflo(uD); dy += bfhi(uD);
    }
    for (; e < s1; ++e) {
      u32 uA = tp[(size_t)csr[e] * 64 + lane];
      ax += bflo(uA); ay += bfhi(uA);
    }
    u32 uS = tp[(size_t)node * 64 + lane];
    float sx = ax + bx + cx + dx + bflo(uS);
    float sy = ay + by + cy + dy + bfhi(uS);

    float dn = dis[node];
    float2 bb = reinterpret_cast<const float2*>(bias)[lane];
    rx = fmaf(dn, sx, bb.x);
    ry = fmaf(dn, sy, bb.y);
    rx = rx > 0.f ? rx : 0.f;
    ry = ry > 0.f ? ry : 0.f;
    if (!POOL) {
      u32 o = (u32)f2bf(rx) | ((u32)f2bf(ry) << 16);
      reinterpret_cast<u32*>(houtb)[(size_t)node * 64 + lane] = o;
    }
  }

  if (POOL) {
    atomicAdd(&pp[lane * 2], rx);
    atomicAdd(&pp[lane * 2 + 1], ry);
    __syncthreads();
    if (tid < 128) atomicAdd(&pooled[tid], pp[tid]);
  }
}

__global__ void k_final(const float* __restrict__ pooled, const float* __restrict__ Wfc,
                        const float* __restrict__ bfc, float* __restrict__ out,
                        float invn) {
  int j = threadIdx.x;
  if (j < 32) {
    float acc = 0.f;
    for (int k = 0; k < 128; ++k) acc = fmaf(pooled[k], Wfc[k * 32 + j], acc);
    out[j] = fmaf(acc, invn, bfc[j]);
  }
}

extern "C" void kernel_launch(void* const* d_in, const int* in_sizes, int n_in,
                              void* d_out, int out_size, void* d_ws, size_t ws_size,
                              hipStream_t stream) {
  const float* x   = (const float*)d_in[0];
  const int*   ei  = (const int*)d_in[1];
  const float* W0  = (const float*)d_in[2];
  const float* b0  = (const float*)d_in[3];
  const float* W1  = (const float*)d_in[4];
  const float* b1  = (const float*)d_in[5];
  const float* W2  = (const float*)d_in[6];
  const float* b2  = (const float*)d_in[7];
  const float* Wfc = (const float*)d_in[8];
  const float* bfc = (const float*)d_in[9];

  const int n = in_sizes[0] / 128;
  const int e = in_sizes[1] / 2;
  const int nb = (n + (1 << BKSH) - 1) >> BKSH;

  char* ws = (char*)d_ws;
  size_t off = 0;
  auto alloc = [&](size_t bytes) -> void* {
    void* p = ws + off;
    off = (off + bytes + 255) & ~(size_t)255;
    return p;
  };
  int*   mode      = (int*)alloc(sizeof(int));
  int*   bucketCnt = (int*)alloc(NBMAX * 4);
  int*   bucketOff = (int*)alloc((NBMAX + 1) * 4);
  int*   bucketCur = (int*)alloc(NBMAX * 4);
  int*   offs      = (int*)alloc((size_t)(n + 1) * 4);
  float* dis       = (float*)alloc((size_t)n * 4);
  int*   csr       = (int*)alloc((size_t)e * 4);
  float* pooled    = (float*)alloc(128 * 4);
  u16*   wp        = (u16*)alloc(3 * 2048 * 8 * 2);
  u16*   tmpb      = (u16*)alloc((size_t)n * 128 * 2);
  u16*   houtb     = (u16*)alloc((size_t)n * 128 * 2);
  int*   pairBuf   = (int*)tmpb;  // alias: pairs consumed (b_fine) before gemm0

  k_init<<<2, 256, 0, stream>>>(ei, mode, bucketCnt, pooled, e, nb);
  b_count<<<192, 256, 0, stream>>>(ei, mode, bucketCnt, e, nb);
  b_bscan<<<1, 256, 0, stream>>>(bucketCnt, bucketOff, bucketCur, nb, e);
  b_scatter<<<(e + SCH - 1) / SCH, 256, 0, stream>>>(ei, mode, bucketCur, pairBuf, e, nb);
  b_fine<<<nb, 512, 0, stream>>>(pairBuf, bucketOff, offs, dis, csr, n, e);

  k_wpack3<<<24, 256, 0, stream>>>(W0, W1, W2, wp);

  int gg = (n + 63) / 64;
  int gn = (n + 3) / 4;

  // layer 0 (reads fp32 x directly)
  k_gemm_mfma<true><<<gg, 256, 0, stream>>>(x, wp, dis, tmpb, n);
  k_gather_bf<false><<<gn, 256, 0, stream>>>(tmpb, csr, offs, dis, b0, houtb, pooled, n);
  // layer 1
  k_gemm_mfma<false><<<gg, 256, 0, stream>>>(houtb, wp + 2048 * 8, dis, tmpb, n);
  k_gather_bf<false><<<gn, 256, 0, stream>>>(tmpb, csr, offs, dis, b1, houtb, pooled, n);
  // layer 2 (gather fuses mean-pool, no hout write)
  k_gemm_mfma<false><<<gg, 256, 0, stream>>>(houtb, wp + 2 * 2048 * 8, dis, tmpb, n);
  k_gather_bf<true><<<gn, 256, 0, stream>>>(tmpb, csr, offs, dis, b2, houtb, pooled, n);

  k_final<<<1, 32, 0, stream>>>(pooled, Wfc, bfc, (float*)d_out, 1.0f / (float)n);
}

// Round 9
// 405.751 us; speedup vs baseline: 2.2914x; 2.2374x over previous
//
#include <hip/hip_runtime.h>
#include <hip/hip_bf16.h>
#include <cstdint>

// ---------------------------------------------------------------------------
// GCN 3-layer forward, bf16 feature pipeline + MFMA GEMM.
// R9: UN-FUSE mean-pool. R6-R8's fused POOL gather did 128 global atomics
//     x 25000 blocks = 3.2M same-line RMWs on pooled[128] (~600us, the
//     structure-independent 609us dispatches in R7/R8 profiles). Pool is a
//     separate 512-block kernel again (65K atomics, ~10us, R4-proven).
//     Gather = exact R4 body. Kept: k_init, k_wpack3, FP32IN GEMM0.
// ---------------------------------------------------------------------------

typedef unsigned short u16;
typedef unsigned int u32;
typedef __attribute__((ext_vector_type(8))) short short8v;
typedef __attribute__((ext_vector_type(4))) float f32x4;

#define NBMAX 256
#define BKSH  9
#define SCH   2048

__device__ inline u16 f2bf(float f) {
  u32 u = __float_as_uint(f);
  u += 0x7fff + ((u >> 16) & 1);  // RNE
  return (u16)(u >> 16);
}
__device__ inline float bflo(u32 u) { return __uint_as_float(u << 16); }
__device__ inline float bfhi(u32 u) { return __uint_as_float(u & 0xffff0000u); }

// --- init: block 0 detects edge dtype, block 1 zeros counters ---------------
__global__ void k_init(const int* __restrict__ ei, int* __restrict__ mode,
                       int* __restrict__ bucketCnt, float* __restrict__ pooled,
                       int e, int nb) {
  if (blockIdx.x == 0) {
    __shared__ int any;
    if (threadIdx.x == 0) any = 0;
    __syncthreads();
    int lim = min(e, 2048);
    int local = 0;
    for (int i = threadIdx.x; i < lim; i += blockDim.x)
      local |= (ei[2 * i + 1] != 0);
    if (local) atomicOr(&any, 1);
    __syncthreads();
    if (threadIdx.x == 0) mode[0] = (any == 0) ? 1 : 0;
  } else {
    int i = threadIdx.x;
    if (i < nb) bucketCnt[i] = 0;
    if (i < 128) pooled[i] = 0.0f;
  }
}

// --- CSR build: 2-level radix by destination --------------------------------
__global__ __launch_bounds__(256) void b_count(const int* __restrict__ ei,
                                               const int* __restrict__ mode,
                                               int* __restrict__ bucketCnt,
                                               int e, int nb) {
  __shared__ int lh[NBMAX];
  int t = threadIdx.x;
  lh[t] = 0;
  __syncthreads();
  int m = mode[0];
  int stride = gridDim.x * 256;
  for (int i = blockIdx.x * 256 + t; i < e; i += stride) {
    long long di = (long long)e + i;
    int d = m ? ei[2 * di] : ei[di];
    atomicAdd(&lh[d >> BKSH], 1);
  }
  __syncthreads();
  if (t < nb && lh[t]) atomicAdd(&bucketCnt[t], lh[t]);
}

__global__ __launch_bounds__(256) void b_bscan(const int* __restrict__ bucketCnt,
                                               int* __restrict__ bucketOff,
                                               int* __restrict__ bucketCur,
                                               int nb, int e) {
  __shared__ int sh[NBMAX];
  int t = threadIdx.x;
  int c = (t < nb) ? bucketCnt[t] : 0;
  sh[t] = c;
  __syncthreads();
  for (int d = 1; d < NBMAX; d <<= 1) {
    int v = (t >= d) ? sh[t - d] : 0;
    __syncthreads();
    sh[t] += v;
    __syncthreads();
  }
  int ex = sh[t] - c;
  if (t < nb) { bucketOff[t] = ex; bucketCur[t] = ex; }
  if (t == 0) bucketOff[nb] = e;
}

__global__ __launch_bounds__(256) void b_scatter(const int* __restrict__ ei,
                                                 const int* __restrict__ mode,
                                                 int* __restrict__ bucketCur,
                                                 int* __restrict__ pairBuf,
                                                 int e, int nb) {
  __shared__ int cnt[NBMAX];
  __shared__ int pre[NBMAX];
  __shared__ int base[NBMAX];
  __shared__ int stage[2 * SCH];
  const int t = threadIdx.x;
  const int chunk0 = blockIdx.x * SCH;
  const int nloc = min(SCH, e - chunk0);
  const int m = mode[0];

  cnt[t] = 0;
  __syncthreads();

  int myS[SCH / 256], myD[SCH / 256], myB[SCH / 256], mySlot[SCH / 256];
#pragma unroll
  for (int j = 0; j < SCH / 256; ++j) {
    int li = j * 256 + t;
    myB[j] = -1;
    if (li < nloc) {
      int i = chunk0 + li;
      long long di = (long long)e + i;
      int s = m ? ei[2 * (long long)i] : ei[i];
      int d = m ? ei[2 * di] : ei[di];
      int b = d >> BKSH;
      myS[j] = s; myD[j] = d; myB[j] = b;
      mySlot[j] = atomicAdd(&cnt[b], 1);
    }
  }
  __syncthreads();

  int c0 = cnt[t];
  pre[t] = c0;
  __syncthreads();
  for (int d = 1; d < NBMAX; d <<= 1) {
    int v = (t >= d) ? pre[t - d] : 0;
    __syncthreads();
    pre[t] += v;
    __syncthreads();
  }
  int myPre = pre[t] - c0;
  if (t < nb && c0 > 0) base[t] = atomicAdd(&bucketCur[t], c0);
  __syncthreads();
  cnt[t] = myPre;
  __syncthreads();

#pragma unroll
  for (int j = 0; j < SCH / 256; ++j) {
    if (myB[j] >= 0) {
      int si = cnt[myB[j]] + mySlot[j];
      stage[2 * si] = myS[j];
      stage[2 * si + 1] = myD[j];
    }
  }
  __syncthreads();

  int wave = t >> 6, lane = t & 63;
  for (int b = wave; b < nb; b += 4) {
    int cb = pre[b] - cnt[b];
    if (cb <= 0) continue;
    int lo = cnt[b];
    size_t gb = (size_t)base[b];
    for (int j = lane; j < 2 * cb; j += 64)
      pairBuf[2 * gb + j] = stage[2 * lo + j];
  }
}

__global__ __launch_bounds__(512) void b_fine(const int* __restrict__ pairBuf,
                                              const int* __restrict__ bucketOff,
                                              int* __restrict__ offs,
                                              float* __restrict__ dis,
                                              int* __restrict__ csr,
                                              int n, int e) {
  const int b = blockIdx.x;
  const int d0 = b << BKSH;
  const int lo = bucketOff[b], hi = bucketOff[b + 1];
  __shared__ int arr[1 << BKSH];
  __shared__ int cur[1 << BKSH];
  const int t = threadIdx.x;
  arr[t] = 0; cur[t] = 0;
  __syncthreads();
  for (int i = lo + t; i < hi; i += 512) {
    int d = pairBuf[2 * (size_t)i + 1];
    atomicAdd(&arr[d - d0], 1);
  }
  __syncthreads();
  int c0 = arr[t];
  __syncthreads();
  for (int dd = 1; dd < 512; dd <<= 1) {
    int v = (t >= dd) ? arr[t - dd] : 0;
    __syncthreads();
    arr[t] += v;
    __syncthreads();
  }
  int epre = arr[t] - c0;
  int gd = d0 + t;
  if (gd < n) {
    offs[gd] = lo + epre;
    dis[gd] = rsqrtf((float)c0 + 1.0f);
  }
  __syncthreads();
  arr[t] = epre;
  __syncthreads();
  for (int i = lo + t; i < hi; i += 512) {
    int s = pairBuf[2 * (size_t)i];
    int d = pairBuf[2 * (size_t)i + 1];
    int ld = d - d0;
    int p = lo + arr[ld] + atomicAdd(&cur[ld], 1);
    csr[p] = s;
  }
  if (b == 0 && t == 0) offs[n] = e;
}

// --- pack all 3 weights fp32 -> MFMA B-fragments bf16 (grid 24) -------------
__global__ __launch_bounds__(256) void k_wpack3(const float* __restrict__ W0,
                                                const float* __restrict__ W1,
                                                const float* __restrict__ W2,
                                                u16* __restrict__ wp) {
  int f = blockIdx.x * 256 + threadIdx.x;
  int wsel = f >> 11;
  int li = f & 2047;
  const float* W = (wsel == 0) ? W0 : (wsel == 1) ? W1 : W2;
  u16* dst = wp + (size_t)wsel * 2048 * 8;
  int ct = li >> 8, kc = (li >> 6) & 3, lane = li & 63;
  int g = lane >> 4, c = lane & 15;
  u32 o[4];
#pragma unroll
  for (int q = 0; q < 4; ++q) {
    int k = kc * 32 + g * 8 + q * 2;
    u16 e0 = f2bf(W[(size_t)k * 128 + ct * 16 + c]);
    u16 e1 = f2bf(W[(size_t)(k + 1) * 128 + ct * 16 + c]);
    o[q] = (u32)e0 | ((u32)e1 << 16);
  }
  uint4 v; v.x = o[0]; v.y = o[1]; v.z = o[2]; v.w = o[3];
  *reinterpret_cast<uint4*>(dst + (size_t)li * 8) = v;
}

// --- GEMM: tmp[r,:] = bf16( dis[r] * (h[r,:] @ W) ) via MFMA ----------------
template <bool FP32IN>
__global__ __launch_bounds__(256) void k_gemm_mfma(const void* __restrict__ hin,
                                                   const u16* __restrict__ wp,
                                                   const float* __restrict__ dis,
                                                   u16* __restrict__ tmpb, int n) {
  __shared__ float eps[64 * 132];
  const int tid = threadIdx.x;
  const int w = tid >> 6, l = tid & 63;
  const int g = l >> 4, c16 = l & 15;
  const int rowbase = blockIdx.x * 64 + w * 16;

  const short8v zero8 = {0, 0, 0, 0, 0, 0, 0, 0};
  short8v a[4];
  int ar = rowbase + c16;
  bool aok = ar < n;
#pragma unroll
  for (int kc = 0; kc < 4; ++kc) {
    if (FP32IN) {
      const float* hrow = (const float*)hin + (size_t)ar * 128;
      short8v s = zero8;
      if (aok) {
        float4 v0 = *reinterpret_cast<const float4*>(hrow + kc * 32 + g * 8);
        float4 v1 = *reinterpret_cast<const float4*>(hrow + kc * 32 + g * 8 + 4);
        s[0] = (short)f2bf(v0.x); s[1] = (short)f2bf(v0.y);
        s[2] = (short)f2bf(v0.z); s[3] = (short)f2bf(v0.w);
        s[4] = (short)f2bf(v1.x); s[5] = (short)f2bf(v1.y);
        s[6] = (short)f2bf(v1.z); s[7] = (short)f2bf(v1.w);
      }
      a[kc] = s;
    } else {
      const u16* hrow = (const u16*)hin + (size_t)ar * 128;
      a[kc] = aok ? *reinterpret_cast<const short8v*>(hrow + kc * 32 + g * 8) : zero8;
    }
  }

  f32x4 acc[8];
#pragma unroll
  for (int ct = 0; ct < 8; ++ct) acc[ct] = f32x4{0.f, 0.f, 0.f, 0.f};

#pragma unroll
  for (int ct = 0; ct < 8; ++ct) {
#pragma unroll
    for (int kc = 0; kc < 4; ++kc) {
      short8v b = *reinterpret_cast<const short8v*>(wp + ((size_t)(ct * 4 + kc) * 64 + l) * 8);
      acc[ct] = __builtin_amdgcn_mfma_f32_16x16x32_bf16(a[kc], b, acc[ct], 0, 0, 0);
    }
  }

#pragma unroll
  for (int j = 0; j < 4; ++j) {
    int rl = w * 16 + g * 4 + j;
    int gr = blockIdx.x * 64 + rl;
    float dn = (gr < n) ? dis[gr] : 0.f;
#pragma unroll
    for (int ct = 0; ct < 8; ++ct)
      eps[rl * 132 + ct * 16 + c16] = acc[ct][j] * dn;
  }
  __syncthreads();

  int rl = tid >> 2, seg = tid & 3;
  int gr = blockIdx.x * 64 + rl;
  if (gr < n) {
    const float* src = &eps[rl * 132 + seg * 32];
#pragma unroll
    for (int q = 0; q < 4; ++q) {
      float4 v0 = *reinterpret_cast<const float4*>(src + q * 8);
      float4 v1 = *reinterpret_cast<const float4*>(src + q * 8 + 4);
      uint4 o;
      o.x = (u32)f2bf(v0.x) | ((u32)f2bf(v0.y) << 16);
      o.y = (u32)f2bf(v0.z) | ((u32)f2bf(v0.w) << 16);
      o.z = (u32)f2bf(v1.x) | ((u32)f2bf(v1.y) << 16);
      o.w = (u32)f2bf(v1.z) | ((u32)f2bf(v1.w) << 16);
      *reinterpret_cast<uint4*>(tmpb + (size_t)gr * 128 + seg * 32 + q * 8) = o;
    }
  }
}

// --- gather (exact R4 body): one wave per node, u32 (2 bf16) per lane -------
__global__ __launch_bounds__(256) void k_gather_bf(const u16* __restrict__ tmpb,
                                                   const int* __restrict__ csr,
                                                   const int* __restrict__ offs,
                                                   const float* __restrict__ dis,
                                                   const float* __restrict__ bias,
                                                   u16* __restrict__ houtb, int n) {
  int node = blockIdx.x * 4 + (threadIdx.x >> 6);
  if (node >= n) return;
  int lane = threadIdx.x & 63;
  const u32* tp = reinterpret_cast<const u32*>(tmpb);
  int s0 = offs[node], s1 = offs[node + 1];

  float ax = 0.f, ay = 0.f, bx = 0.f, by = 0.f;
  float cx = 0.f, cy = 0.f, dx = 0.f, dy = 0.f;
  int e = s0;
  for (; e + 3 < s1; e += 4) {
    u32 uA = tp[(size_t)csr[e] * 64 + lane];
    u32 uB = tp[(size_t)csr[e + 1] * 64 + lane];
    u32 uC = tp[(size_t)csr[e + 2] * 64 + lane];
    u32 uD = tp[(size_t)csr[e + 3] * 64 + lane];
    ax += bflo(uA); ay += bfhi(uA); bx += bflo(uB); by += bfhi(uB);
    cx += bflo(uC); cy += bfhi(uC); dx += bflo(uD); dy += bfhi(uD);
  }
  for (; e < s1; ++e) {
    u32 uA = tp[(size_t)csr[e] * 64 + lane];
    ax += bflo(uA); ay += bfhi(uA);
  }
  u32 uS = tp[(size_t)node * 64 + lane];
  float sx = ax + bx + cx + dx + bflo(uS);
  float sy = ay + by + cy + dy + bfhi(uS);

  float dn = dis[node];
  float2 bb = reinterpret_cast<const float2*>(bias)[lane];
  float rx = fmaf(dn, sx, bb.x);
  float ry = fmaf(dn, sy, bb.y);
  rx = rx > 0.f ? rx : 0.f;
  ry = ry > 0.f ? ry : 0.f;
  u32 o = (u32)f2bf(rx) | ((u32)f2bf(ry) << 16);
  reinterpret_cast<u32*>(houtb)[(size_t)node * 64 + lane] = o;
}

// --- mean-pool column sums (bf16 in, fp32 out); 512 blocks -> 65K atomics ---
__global__ __launch_bounds__(256) void k_pool_bf(const u16* __restrict__ h,
                                                 float* __restrict__ pooled, int n) {
  int lane = threadIdx.x & 63, wv = threadIdx.x >> 6;
  const u32* hp = reinterpret_cast<const u32*>(h);
  float sx = 0.f, sy = 0.f;
  for (int r = blockIdx.x * 4 + wv; r < n; r += gridDim.x * 4) {
    u32 u = hp[(size_t)r * 64 + lane];
    sx += bflo(u); sy += bfhi(u);
  }
  __shared__ float red[2][256];
  red[0][threadIdx.x] = sx;
  red[1][threadIdx.x] = sy;
  __syncthreads();
  if (threadIdx.x < 64) {
    float tx = red[0][threadIdx.x] + red[0][threadIdx.x + 64] +
               red[0][threadIdx.x + 128] + red[0][threadIdx.x + 192];
    float ty = red[1][threadIdx.x] + red[1][threadIdx.x + 64] +
               red[1][threadIdx.x + 128] + red[1][threadIdx.x + 192];
    atomicAdd(&pooled[threadIdx.x * 2], tx);
    atomicAdd(&pooled[threadIdx.x * 2 + 1], ty);
  }
}

__global__ void k_final(const float* __restrict__ pooled, const float* __restrict__ Wfc,
                        const float* __restrict__ bfc, float* __restrict__ out,
                        float invn) {
  int j = threadIdx.x;
  if (j < 32) {
    float acc = 0.f;
    for (int k = 0; k < 128; ++k) acc = fmaf(pooled[k], Wfc[k * 32 + j], acc);
    out[j] = fmaf(acc, invn, bfc[j]);
  }
}

extern "C" void kernel_launch(void* const* d_in, const int* in_sizes, int n_in,
                              void* d_out, int out_size, void* d_ws, size_t ws_size,
                              hipStream_t stream) {
  const float* x   = (const float*)d_in[0];
  const int*   ei  = (const int*)d_in[1];
  const float* W0  = (const float*)d_in[2];
  const float* b0  = (const float*)d_in[3];
  const float* W1  = (const float*)d_in[4];
  const float* b1  = (const float*)d_in[5];
  const float* W2  = (const float*)d_in[6];
  const float* b2  = (const float*)d_in[7];
  const float* Wfc = (const float*)d_in[8];
  const float* bfc = (const float*)d_in[9];

  const int n = in_sizes[0] / 128;
  const int e = in_sizes[1] / 2;
  const int nb = (n + (1 << BKSH) - 1) >> BKSH;

  char* ws = (char*)d_ws;
  size_t off = 0;
  auto alloc = [&](size_t bytes) -> void* {
    void* p = ws + off;
    off = (off + bytes + 255) & ~(size_t)255;
    return p;
  };
  int*   mode      = (int*)alloc(sizeof(int));
  int*   bucketCnt = (int*)alloc(NBMAX * 4);
  int*   bucketOff = (int*)alloc((NBMAX + 1) * 4);
  int*   bucketCur = (int*)alloc(NBMAX * 4);
  int*   offs      = (int*)alloc((size_t)(n + 1) * 4);
  float* dis       = (float*)alloc((size_t)n * 4);
  int*   csr       = (int*)alloc((size_t)e * 4);
  float* pooled    = (float*)alloc(128 * 4);
  u16*   wp        = (u16*)alloc(3 * 2048 * 8 * 2);
  u16*   tmpb      = (u16*)alloc((size_t)n * 128 * 2);
  u16*   houtb     = (u16*)alloc((size_t)n * 128 * 2);
  int*   pairBuf   = (int*)tmpb;  // alias: pairs consumed (b_fine) before gemm0

  k_init<<<2, 256, 0, stream>>>(ei, mode, bucketCnt, pooled, e, nb);
  b_count<<<192, 256, 0, stream>>>(ei, mode, bucketCnt, e, nb);
  b_bscan<<<1, 256, 0, stream>>>(bucketCnt, bucketOff, bucketCur, nb, e);
  b_scatter<<<(e + SCH - 1) / SCH, 256, 0, stream>>>(ei, mode, bucketCur, pairBuf, e, nb);
  b_fine<<<nb, 512, 0, stream>>>(pairBuf, bucketOff, offs, dis, csr, n, e);

  k_wpack3<<<24, 256, 0, stream>>>(W0, W1, W2, wp);

  int gg = (n + 63) / 64;
  int gn = (n + 3) / 4;

  // layer 0 (reads fp32 x directly)
  k_gemm_mfma<true><<<gg, 256, 0, stream>>>(x, wp, dis, tmpb, n);
  k_gather_bf<<<gn, 256, 0, stream>>>(tmpb, csr, offs, dis, b0, houtb, n);
  // layer 1
  k_gemm_mfma<false><<<gg, 256, 0, stream>>>(houtb, wp + 2048 * 8, dis, tmpb, n);
  k_gather_bf<<<gn, 256, 0, stream>>>(tmpb, csr, offs, dis, b1, houtb, n);
  // layer 2
  k_gemm_mfma<false><<<gg, 256, 0, stream>>>(houtb, wp + 2 * 2048 * 8, dis, tmpb, n);
  k_gather_bf<<<gn, 256, 0, stream>>>(tmpb, csr, offs, dis, b2, houtb, n);

  k_pool_bf<<<512, 256, 0, stream>>>(houtb, pooled, n);
  k_final<<<1, 32, 0, stream>>>(pooled, Wfc, bfc, (float*)d_out, 1.0f / (float)n);
}

// Round 10
// 369.117 us; speedup vs baseline: 2.5189x; 1.0992x over previous
//
#include <hip/hip_runtime.h>
#include <hip/hip_bf16.h>
#include <cstdint>

// ---------------------------------------------------------------------------
// GCN 3-layer forward, bf16 pipeline + MFMA GEMM + fp8 gather operand.
// R10: tmpb stored as fp8 e4m3 (x16 pre-scale folded into GEMM's dis mul,
//      /16 folded into gather's dis mul). Rationale: gather FETCH measured
//      == 8 XCDs x full tmpb footprint (non-coherent L2 floor, R4/R9), so
//      halving the footprint halves the fetch floor: 190 -> ~102 MB/layer.
//      houtb / GEMM inputs / accum stay bf16+fp32 (streamed, cheap, precise).
// ---------------------------------------------------------------------------

typedef unsigned short u16;
typedef unsigned int u32;
typedef unsigned char u8;
typedef __attribute__((ext_vector_type(8))) short short8v;
typedef __attribute__((ext_vector_type(4))) float f32x4;

#define NBMAX 256
#define BKSH  9
#define SCH   2048

__device__ inline u16 f2bf(float f) {
  u32 u = __float_as_uint(f);
  u += 0x7fff + ((u >> 16) & 1);  // RNE
  return (u16)(u >> 16);
}
__device__ inline float bflo(u32 u) { return __uint_as_float(u << 16); }
__device__ inline float bfhi(u32 u) { return __uint_as_float(u & 0xffff0000u); }

// --- init: block 0 detects edge dtype, block 1 zeros counters ---------------
__global__ void k_init(const int* __restrict__ ei, int* __restrict__ mode,
                       int* __restrict__ bucketCnt, float* __restrict__ pooled,
                       int e, int nb) {
  if (blockIdx.x == 0) {
    __shared__ int any;
    if (threadIdx.x == 0) any = 0;
    __syncthreads();
    int lim = min(e, 2048);
    int local = 0;
    for (int i = threadIdx.x; i < lim; i += blockDim.x)
      local |= (ei[2 * i + 1] != 0);
    if (local) atomicOr(&any, 1);
    __syncthreads();
    if (threadIdx.x == 0) mode[0] = (any == 0) ? 1 : 0;
  } else {
    int i = threadIdx.x;
    if (i < nb) bucketCnt[i] = 0;
    if (i < 128) pooled[i] = 0.0f;
  }
}

// --- CSR build: 2-level radix by destination --------------------------------
__global__ __launch_bounds__(256) void b_count(const int* __restrict__ ei,
                                               const int* __restrict__ mode,
                                               int* __restrict__ bucketCnt,
                                               int e, int nb) {
  __shared__ int lh[NBMAX];
  int t = threadIdx.x;
  lh[t] = 0;
  __syncthreads();
  int m = mode[0];
  int stride = gridDim.x * 256;
  for (int i = blockIdx.x * 256 + t; i < e; i += stride) {
    long long di = (long long)e + i;
    int d = m ? ei[2 * di] : ei[di];
    atomicAdd(&lh[d >> BKSH], 1);
  }
  __syncthreads();
  if (t < nb && lh[t]) atomicAdd(&bucketCnt[t], lh[t]);
}

__global__ __launch_bounds__(256) void b_bscan(const int* __restrict__ bucketCnt,
                                               int* __restrict__ bucketOff,
                                               int* __restrict__ bucketCur,
                                               int nb, int e) {
  __shared__ int sh[NBMAX];
  int t = threadIdx.x;
  int c = (t < nb) ? bucketCnt[t] : 0;
  sh[t] = c;
  __syncthreads();
  for (int d = 1; d < NBMAX; d <<= 1) {
    int v = (t >= d) ? sh[t - d] : 0;
    __syncthreads();
    sh[t] += v;
    __syncthreads();
  }
  int ex = sh[t] - c;
  if (t < nb) { bucketOff[t] = ex; bucketCur[t] = ex; }
  if (t == 0) bucketOff[nb] = e;
}

__global__ __launch_bounds__(256) void b_scatter(const int* __restrict__ ei,
                                                 const int* __restrict__ mode,
                                                 int* __restrict__ bucketCur,
                                                 int* __restrict__ pairBuf,
                                                 int e, int nb) {
  __shared__ int cnt[NBMAX];
  __shared__ int pre[NBMAX];
  __shared__ int base[NBMAX];
  __shared__ int stage[2 * SCH];
  const int t = threadIdx.x;
  const int chunk0 = blockIdx.x * SCH;
  const int nloc = min(SCH, e - chunk0);
  const int m = mode[0];

  cnt[t] = 0;
  __syncthreads();

  int myS[SCH / 256], myD[SCH / 256], myB[SCH / 256], mySlot[SCH / 256];
#pragma unroll
  for (int j = 0; j < SCH / 256; ++j) {
    int li = j * 256 + t;
    myB[j] = -1;
    if (li < nloc) {
      int i = chunk0 + li;
      long long di = (long long)e + i;
      int s = m ? ei[2 * (long long)i] : ei[i];
      int d = m ? ei[2 * di] : ei[di];
      int b = d >> BKSH;
      myS[j] = s; myD[j] = d; myB[j] = b;
      mySlot[j] = atomicAdd(&cnt[b], 1);
    }
  }
  __syncthreads();

  int c0 = cnt[t];
  pre[t] = c0;
  __syncthreads();
  for (int d = 1; d < NBMAX; d <<= 1) {
    int v = (t >= d) ? pre[t - d] : 0;
    __syncthreads();
    pre[t] += v;
    __syncthreads();
  }
  int myPre = pre[t] - c0;
  if (t < nb && c0 > 0) base[t] = atomicAdd(&bucketCur[t], c0);
  __syncthreads();
  cnt[t] = myPre;
  __syncthreads();

#pragma unroll
  for (int j = 0; j < SCH / 256; ++j) {
    if (myB[j] >= 0) {
      int si = cnt[myB[j]] + mySlot[j];
      stage[2 * si] = myS[j];
      stage[2 * si + 1] = myD[j];
    }
  }
  __syncthreads();

  int wave = t >> 6, lane = t & 63;
  for (int b = wave; b < nb; b += 4) {
    int cb = pre[b] - cnt[b];
    if (cb <= 0) continue;
    int lo = cnt[b];
    size_t gb = (size_t)base[b];
    for (int j = lane; j < 2 * cb; j += 64)
      pairBuf[2 * gb + j] = stage[2 * lo + j];
  }
}

__global__ __launch_bounds__(512) void b_fine(const int* __restrict__ pairBuf,
                                              const int* __restrict__ bucketOff,
                                              int* __restrict__ offs,
                                              float* __restrict__ dis,
                                              int* __restrict__ csr,
                                              int n, int e) {
  const int b = blockIdx.x;
  const int d0 = b << BKSH;
  const int lo = bucketOff[b], hi = bucketOff[b + 1];
  __shared__ int arr[1 << BKSH];
  __shared__ int cur[1 << BKSH];
  const int t = threadIdx.x;
  arr[t] = 0; cur[t] = 0;
  __syncthreads();
  for (int i = lo + t; i < hi; i += 512) {
    int d = pairBuf[2 * (size_t)i + 1];
    atomicAdd(&arr[d - d0], 1);
  }
  __syncthreads();
  int c0 = arr[t];
  __syncthreads();
  for (int dd = 1; dd < 512; dd <<= 1) {
    int v = (t >= dd) ? arr[t - dd] : 0;
    __syncthreads();
    arr[t] += v;
    __syncthreads();
  }
  int epre = arr[t] - c0;
  int gd = d0 + t;
  if (gd < n) {
    offs[gd] = lo + epre;
    dis[gd] = rsqrtf((float)c0 + 1.0f);
  }
  __syncthreads();
  arr[t] = epre;
  __syncthreads();
  for (int i = lo + t; i < hi; i += 512) {
    int s = pairBuf[2 * (size_t)i];
    int d = pairBuf[2 * (size_t)i + 1];
    int ld = d - d0;
    int p = lo + arr[ld] + atomicAdd(&cur[ld], 1);
    csr[p] = s;
  }
  if (b == 0 && t == 0) offs[n] = e;
}

// --- pack all 3 weights fp32 -> MFMA B-fragments bf16 (grid 24) -------------
__global__ __launch_bounds__(256) void k_wpack3(const float* __restrict__ W0,
                                                const float* __restrict__ W1,
                                                const float* __restrict__ W2,
                                                u16* __restrict__ wp) {
  int f = blockIdx.x * 256 + threadIdx.x;
  int wsel = f >> 11;
  int li = f & 2047;
  const float* W = (wsel == 0) ? W0 : (wsel == 1) ? W1 : W2;
  u16* dst = wp + (size_t)wsel * 2048 * 8;
  int ct = li >> 8, kc = (li >> 6) & 3, lane = li & 63;
  int g = lane >> 4, c = lane & 15;
  u32 o[4];
#pragma unroll
  for (int q = 0; q < 4; ++q) {
    int k = kc * 32 + g * 8 + q * 2;
    u16 e0 = f2bf(W[(size_t)k * 128 + ct * 16 + c]);
    u16 e1 = f2bf(W[(size_t)(k + 1) * 128 + ct * 16 + c]);
    o[q] = (u32)e0 | ((u32)e1 << 16);
  }
  uint4 v; v.x = o[0]; v.y = o[1]; v.z = o[2]; v.w = o[3];
  *reinterpret_cast<uint4*>(dst + (size_t)li * 8) = v;
}

// --- GEMM: tmp[r,:] = fp8( 16 * dis[r] * (h[r,:] @ W) ) via MFMA ------------
template <bool FP32IN>
__global__ __launch_bounds__(256) void k_gemm_mfma(const void* __restrict__ hin,
                                                   const u16* __restrict__ wp,
                                                   const float* __restrict__ dis,
                                                   u8* __restrict__ tmpf8, int n) {
  __shared__ float eps[64 * 132];
  const int tid = threadIdx.x;
  const int w = tid >> 6, l = tid & 63;
  const int g = l >> 4, c16 = l & 15;
  const int rowbase = blockIdx.x * 64 + w * 16;

  const short8v zero8 = {0, 0, 0, 0, 0, 0, 0, 0};
  short8v a[4];
  int ar = rowbase + c16;
  bool aok = ar < n;
#pragma unroll
  for (int kc = 0; kc < 4; ++kc) {
    if (FP32IN) {
      const float* hrow = (const float*)hin + (size_t)ar * 128;
      short8v s = zero8;
      if (aok) {
        float4 v0 = *reinterpret_cast<const float4*>(hrow + kc * 32 + g * 8);
        float4 v1 = *reinterpret_cast<const float4*>(hrow + kc * 32 + g * 8 + 4);
        s[0] = (short)f2bf(v0.x); s[1] = (short)f2bf(v0.y);
        s[2] = (short)f2bf(v0.z); s[3] = (short)f2bf(v0.w);
        s[4] = (short)f2bf(v1.x); s[5] = (short)f2bf(v1.y);
        s[6] = (short)f2bf(v1.z); s[7] = (short)f2bf(v1.w);
      }
      a[kc] = s;
    } else {
      const u16* hrow = (const u16*)hin + (size_t)ar * 128;
      a[kc] = aok ? *reinterpret_cast<const short8v*>(hrow + kc * 32 + g * 8) : zero8;
    }
  }

  f32x4 acc[8];
#pragma unroll
  for (int ct = 0; ct < 8; ++ct) acc[ct] = f32x4{0.f, 0.f, 0.f, 0.f};

#pragma unroll
  for (int ct = 0; ct < 8; ++ct) {
#pragma unroll
    for (int kc = 0; kc < 4; ++kc) {
      short8v b = *reinterpret_cast<const short8v*>(wp + ((size_t)(ct * 4 + kc) * 64 + l) * 8);
      acc[ct] = __builtin_amdgcn_mfma_f32_16x16x32_bf16(a[kc], b, acc[ct], 0, 0, 0);
    }
  }

  // scale by 16*dis[row] (x16 clears fp8 subnormal region; gather divides out)
#pragma unroll
  for (int j = 0; j < 4; ++j) {
    int rl = w * 16 + g * 4 + j;
    int gr = blockIdx.x * 64 + rl;
    float dn = (gr < n) ? dis[gr] * 16.0f : 0.f;
#pragma unroll
    for (int ct = 0; ct < 8; ++ct)
      eps[rl * 132 + ct * 16 + c16] = acc[ct][j] * dn;
  }
  __syncthreads();

  // readback: thread -> (row rl, 32-col segment), pack fp8 and store 32B
  int rl = tid >> 2, seg = tid & 3;
  int gr = blockIdx.x * 64 + rl;
  if (gr < n) {
    const float* src = &eps[rl * 132 + seg * 32];
    u32 wds[8];
#pragma unroll
    for (int q = 0; q < 4; ++q) {
      float4 v0 = *reinterpret_cast<const float4*>(src + q * 8);
      float4 v1 = *reinterpret_cast<const float4*>(src + q * 8 + 4);
      int p0 = __builtin_amdgcn_cvt_pk_fp8_f32(v0.x, v0.y, 0, false);
      p0 = __builtin_amdgcn_cvt_pk_fp8_f32(v0.z, v0.w, p0, true);
      int p1 = __builtin_amdgcn_cvt_pk_fp8_f32(v1.x, v1.y, 0, false);
      p1 = __builtin_amdgcn_cvt_pk_fp8_f32(v1.z, v1.w, p1, true);
      wds[q * 2] = (u32)p0;
      wds[q * 2 + 1] = (u32)p1;
    }
    uint4 o0; o0.x = wds[0]; o0.y = wds[1]; o0.z = wds[2]; o0.w = wds[3];
    uint4 o1; o1.x = wds[4]; o1.y = wds[5]; o1.z = wds[6]; o1.w = wds[7];
    *reinterpret_cast<uint4*>(tmpf8 + (size_t)gr * 128 + seg * 32) = o0;
    *reinterpret_cast<uint4*>(tmpf8 + (size_t)gr * 128 + seg * 32 + 16) = o1;
  }
}

// --- gather: one wave per node, u16 (2 fp8 cols) per lane, ILP-4 ------------
// wave-uniform csr index (R4-proven); fp32 accumulate; /16 folded into dis.
__global__ __launch_bounds__(256) void k_gather_bf(const u8* __restrict__ tmpf8,
                                                   const int* __restrict__ csr,
                                                   const int* __restrict__ offs,
                                                   const float* __restrict__ dis,
                                                   const float* __restrict__ bias,
                                                   u16* __restrict__ houtb, int n) {
  int node = blockIdx.x * 4 + (threadIdx.x >> 6);
  if (node >= n) return;
  int lane = threadIdx.x & 63;
  const u16* tp = reinterpret_cast<const u16*>(tmpf8);
  int s0 = offs[node], s1 = offs[node + 1];

  float ax = 0.f, ay = 0.f, bx = 0.f, by = 0.f;
  float cx = 0.f, cy = 0.f, dx = 0.f, dy = 0.f;
  int e = s0;
  for (; e + 3 < s1; e += 4) {
    int uA = tp[(size_t)csr[e] * 64 + lane];
    int uB = tp[(size_t)csr[e + 1] * 64 + lane];
    int uC = tp[(size_t)csr[e + 2] * 64 + lane];
    int uD = tp[(size_t)csr[e + 3] * 64 + lane];
    ax += __builtin_amdgcn_cvt_f32_fp8(uA, 0);
    ay += __builtin_amdgcn_cvt_f32_fp8(uA, 1);
    bx += __builtin_amdgcn_cvt_f32_fp8(uB, 0);
    by += __builtin_amdgcn_cvt_f32_fp8(uB, 1);
    cx += __builtin_amdgcn_cvt_f32_fp8(uC, 0);
    cy += __builtin_amdgcn_cvt_f32_fp8(uC, 1);
    dx += __builtin_amdgcn_cvt_f32_fp8(uD, 0);
    dy += __builtin_amdgcn_cvt_f32_fp8(uD, 1);
  }
  for (; e < s1; ++e) {
    int uA = tp[(size_t)csr[e] * 64 + lane];
    ax += __builtin_amdgcn_cvt_f32_fp8(uA, 0);
    ay += __builtin_amdgcn_cvt_f32_fp8(uA, 1);
  }
  int uS = tp[(size_t)node * 64 + lane];
  float sx = ax + bx + cx + dx + __builtin_amdgcn_cvt_f32_fp8(uS, 0);
  float sy = ay + by + cy + dy + __builtin_amdgcn_cvt_f32_fp8(uS, 1);

  float dn = dis[node] * 0.0625f;  // /16 undoes the fp8 pre-scale
  float2 bb = reinterpret_cast<const float2*>(bias)[lane];
  float rx = fmaf(dn, sx, bb.x);
  float ry = fmaf(dn, sy, bb.y);
  rx = rx > 0.f ? rx : 0.f;
  ry = ry > 0.f ? ry : 0.f;
  u32 o = (u32)f2bf(rx) | ((u32)f2bf(ry) << 16);
  reinterpret_cast<u32*>(houtb)[(size_t)node * 64 + lane] = o;
}

// --- mean-pool column sums (bf16 in, fp32 out); 512 blocks -> 65K atomics ---
__global__ __launch_bounds__(256) void k_pool_bf(const u16* __restrict__ h,
                                                 float* __restrict__ pooled, int n) {
  int lane = threadIdx.x & 63, wv = threadIdx.x >> 6;
  const u32* hp = reinterpret_cast<const u32*>(h);
  float sx = 0.f, sy = 0.f;
  for (int r = blockIdx.x * 4 + wv; r < n; r += gridDim.x * 4) {
    u32 u = hp[(size_t)r * 64 + lane];
    sx += bflo(u); sy += bfhi(u);
  }
  __shared__ float red[2][256];
  red[0][threadIdx.x] = sx;
  red[1][threadIdx.x] = sy;
  __syncthreads();
  if (threadIdx.x < 64) {
    float tx = red[0][threadIdx.x] + red[0][threadIdx.x + 64] +
               red[0][threadIdx.x + 128] + red[0][threadIdx.x + 192];
    float ty = red[1][threadIdx.x] + red[1][threadIdx.x + 64] +
               red[1][threadIdx.x + 128] + red[1][threadIdx.x + 192];
    atomicAdd(&pooled[threadIdx.x * 2], tx);
    atomicAdd(&pooled[threadIdx.x * 2 + 1], ty);
  }
}

__global__ void k_final(const float* __restrict__ pooled, const float* __restrict__ Wfc,
                        const float* __restrict__ bfc, float* __restrict__ out,
                        float invn) {
  int j = threadIdx.x;
  if (j < 32) {
    float acc = 0.f;
    for (int k = 0; k < 128; ++k) acc = fmaf(pooled[k], Wfc[k * 32 + j], acc);
    out[j] = fmaf(acc, invn, bfc[j]);
  }
}

extern "C" void kernel_launch(void* const* d_in, const int* in_sizes, int n_in,
                              void* d_out, int out_size, void* d_ws, size_t ws_size,
                              hipStream_t stream) {
  const float* x   = (const float*)d_in[0];
  const int*   ei  = (const int*)d_in[1];
  const float* W0  = (const float*)d_in[2];
  const float* b0  = (const float*)d_in[3];
  const float* W1  = (const float*)d_in[4];
  const float* b1  = (const float*)d_in[5];
  const float* W2  = (const float*)d_in[6];
  const float* b2  = (const float*)d_in[7];
  const float* Wfc = (const float*)d_in[8];
  const float* bfc = (const float*)d_in[9];

  const int n = in_sizes[0] / 128;
  const int e = in_sizes[1] / 2;
  const int nb = (n + (1 << BKSH) - 1) >> BKSH;

  char* ws = (char*)d_ws;
  size_t off = 0;
  auto alloc = [&](size_t bytes) -> void* {
    void* p = ws + off;
    off = (off + bytes + 255) & ~(size_t)255;
    return p;
  };
  int*   mode      = (int*)alloc(sizeof(int));
  int*   bucketCnt = (int*)alloc(NBMAX * 4);
  int*   bucketOff = (int*)alloc((NBMAX + 1) * 4);
  int*   bucketCur = (int*)alloc(NBMAX * 4);
  int*   offs      = (int*)alloc((size_t)(n + 1) * 4);
  float* dis       = (float*)alloc((size_t)n * 4);
  int*   csr       = (int*)alloc((size_t)e * 4);
  float* pooled    = (float*)alloc(128 * 4);
  u16*   wp        = (u16*)alloc(3 * 2048 * 8 * 2);
  u8*    tmpf8     = (u8*)alloc((size_t)n * 128);
  u16*   houtb     = (u16*)alloc((size_t)n * 128 * 2);
  int*   pairBuf   = (int*)houtb;  // alias: pairs consumed (b_fine) before gather0 writes houtb

  k_init<<<2, 256, 0, stream>>>(ei, mode, bucketCnt, pooled, e, nb);
  b_count<<<192, 256, 0, stream>>>(ei, mode, bucketCnt, e, nb);
  b_bscan<<<1, 256, 0, stream>>>(bucketCnt, bucketOff, bucketCur, nb, e);
  b_scatter<<<(e + SCH - 1) / SCH, 256, 0, stream>>>(ei, mode, bucketCur, pairBuf, e, nb);
  b_fine<<<nb, 512, 0, stream>>>(pairBuf, bucketOff, offs, dis, csr, n, e);

  k_wpack3<<<24, 256, 0, stream>>>(W0, W1, W2, wp);

  int gg = (n + 63) / 64;
  int gn = (n + 3) / 4;

  // layer 0 (reads fp32 x directly)
  k_gemm_mfma<true><<<gg, 256, 0, stream>>>(x, wp, dis, tmpf8, n);
  k_gather_bf<<<gn, 256, 0, stream>>>(tmpf8, csr, offs, dis, b0, houtb, n);
  // layer 1
  k_gemm_mfma<false><<<gg, 256, 0, stream>>>(houtb, wp + 2048 * 8, dis, tmpf8, n);
  k_gather_bf<<<gn, 256, 0, stream>>>(tmpf8, csr, offs, dis, b1, houtb, n);
  // layer 2
  k_gemm_mfma<false><<<gg, 256, 0, stream>>>(houtb, wp + 2 * 2048 * 8, dis, tmpf8, n);
  k_gather_bf<<<gn, 256, 0, stream>>>(tmpf8, csr, offs, dis, b2, houtb, n);

  k_pool_bf<<<512, 256, 0, stream>>>(houtb, pooled, n);
  k_final<<<1, 32, 0, stream>>>(pooled, Wfc, bfc, (float*)d_out, 1.0f / (float)n);
}